// Round 4
// baseline (291.575 us; speedup 1.0000x reference)
//
#include <hip/hip_runtime.h>
#include <math.h>

#define C    128
#define C4   32
#define NN   2304          // 48*48
#define BN_EPS 1e-5f
#define NEG_INF -3.402823466e38f
#define LOG2E 1.4426950408889634f

typedef short bf16x8 __attribute__((ext_vector_type(8)));
typedef float f32x4 __attribute__((ext_vector_type(4)));

__device__ inline unsigned short f2bf(float f) {
    unsigned int u = __float_as_uint(f);
    u += 0x7fffu + ((u >> 16) & 1u);
    return (unsigned short)(u >> 16);
}

// pack two fp32 -> packed bf16 pair (low = a, high = b), RNE
__device__ inline unsigned int pk2bf(float a, float b) {
#if __has_builtin(__builtin_amdgcn_cvt_pk_bf16_f32)
    typedef __bf16 bf2 __attribute__((ext_vector_type(2)));
    bf2 v = __builtin_amdgcn_cvt_pk_bf16_f32(a, b);
    return __builtin_bit_cast(unsigned int, v);
#else
    unsigned int ua = __float_as_uint(a); ua += 0x7fffu + ((ua >> 16) & 1u);
    unsigned int ub = __float_as_uint(b); ub += 0x7fffu + ((ub >> 16) & 1u);
    return __builtin_amdgcn_perm(ub, ua, 0x07060302u);
#endif
}

__device__ inline float fexp2(float x) {
#if __has_builtin(__builtin_amdgcn_exp2f)
    return __builtin_amdgcn_exp2f(x);
#else
    return __expf(x * 0.69314718055994531f);
#endif
}

// ---------------- workspace layout ----------------
// ushort region:
//   Kt  [16][2304][32]  @0         (1179648)   NOTE: K pre-scaled by log2(e)
//   Qt  [16][2304][32]  @1179648   (1179648)
//   Vf  [16][128][2304] @2359296   (4718592)
//   wkq_bf [32][128]    @7077888   (4096)
//   wv_bf  [128][128]   @7081984   (16384)
//   wred_bf[128][256]   @7098368   (32768)
// float region:
//   bmax[16*324], bsum[16*324], Ms[16], Sinv[16], kq_sh[32], v_sh[128], red_sh[128]

__global__ __launch_bounds__(256) void k_wprep(
    const float* __restrict__ wkq, const float* __restrict__ kq_g,
    const float* __restrict__ kq_b, const float* __restrict__ kq_m,
    const float* __restrict__ kq_v,
    const float* __restrict__ wv, const float* __restrict__ v_g,
    const float* __restrict__ v_b, const float* __restrict__ v_m,
    const float* __restrict__ v_v,
    const float* __restrict__ wred, const float* __restrict__ red_g,
    const float* __restrict__ red_b, const float* __restrict__ red_m,
    const float* __restrict__ red_v,
    unsigned short* __restrict__ wkq_bf, unsigned short* __restrict__ wv_bf,
    unsigned short* __restrict__ wred_bf,
    float* __restrict__ kq_sh, float* __restrict__ v_sh, float* __restrict__ red_sh)
{
    const int t = blockIdx.x * 256 + threadIdx.x;
    if (t < 4096) {
        const int o = t >> 7;
        const float sc = kq_g[o] * rsqrtf(kq_v[o] + BN_EPS);
        wkq_bf[t] = f2bf(wkq[t] * sc);
        if ((t & 127) == 0) kq_sh[o] = kq_b[o] - kq_m[o] * sc;
    } else if (t < 4096 + 16384) {
        const int e = t - 4096;
        const int o = e >> 7;
        const float sc = v_g[o] * rsqrtf(v_v[o] + BN_EPS);
        wv_bf[e] = f2bf(wv[e] * sc);
        if ((e & 127) == 0) v_sh[o] = v_b[o] - v_m[o] * sc;
    } else if (t < 4096 + 16384 + 32768) {
        const int e = t - 20480;
        const int o = e >> 8;
        const float sc = red_g[o] * rsqrtf(red_v[o] + BN_EPS);
        wred_bf[e] = f2bf(wred[e] * sc);
        if ((e & 255) == 0) red_sh[o] = red_b[o] - red_m[o] * sc;
    }
}

// ---- unified MFMA 1x1-conv kernel ----
// MODE 0: fp32 out rows [b][o][n] into outf                 (reduce conv)
// MODE 1: bf16 out  [b][o][n] into outb0 (Vf)               (V conv)
// MODE 2: bf16 transposed [b][n][32o] into outb0/outb1; K output (z==0)
//         additionally scaled by log2(e) for exp2-domain softmax
template<int CIN, int M, int NTILE, int MODE>
__global__ __launch_bounds__(256) void k_conv(
    const float* __restrict__ x0, const float* __restrict__ x1, size_t xbstride,
    const unsigned short* __restrict__ wbf, const float* __restrict__ shift,
    float* __restrict__ outf, unsigned short* __restrict__ outb0,
    unsigned short* __restrict__ outb1)
{
    constexpr int R  = NTILE / 16;
    constexpr int MT = 2;
    constexpr int NT = (M == 32) ? 2 : (NTILE / 16);
    __shared__ unsigned short Xs[NTILE][40];

    const int tid = threadIdx.x;
    const int w = tid >> 6, lane = tid & 63;
    const int quad = lane >> 4, l16 = lane & 15;
    const int b = blockIdx.y, n0 = blockIdx.x * NTILE;
    const int mbase = (M == 32) ? 0 : w * 32;
    const int nbase = (M == 32) ? w * 32 : 0;

    const float* xin = (blockIdx.z ? x1 : x0) + (size_t)b * xbstride;
    const int p = tid & 15, g = tid >> 4;

    f32x4 acc[MT][NT];
#pragma unroll
    for (int mt = 0; mt < MT; mt++)
#pragma unroll
        for (int nt = 0; nt < NT; nt++) acc[mt][nt] = (f32x4){0.f, 0.f, 0.f, 0.f};

    for (int c0 = 0; c0 < CIN; c0 += 32) {
        __syncthreads();
        {
            const float* xr = xin + (size_t)(c0 + 2 * p) * NN + n0 + g * R;
            float av[R], bv[R];
#pragma unroll
            for (int i4 = 0; i4 < R; i4 += 4) {
                *(float4*)&av[i4] = *(const float4*)&xr[i4];
                *(float4*)&bv[i4] = *(const float4*)&xr[NN + i4];
            }
            unsigned int* Xw = (unsigned int*)Xs;
#pragma unroll
            for (int i = 0; i < R; i++)
                Xw[(g * R + i) * 20 + p] = pk2bf(av[i], bv[i]);
        }
        __syncthreads();
        bf16x8 af[MT];
#pragma unroll
        for (int mt = 0; mt < MT; mt++)
            af[mt] = *(const bf16x8*)&wbf[(size_t)(mbase + mt * 16 + l16) * CIN + c0 + quad * 8];
#pragma unroll
        for (int nt = 0; nt < NT; nt++) {
            const bf16x8 bfr = *(const bf16x8*)&Xs[nbase + nt * 16 + l16][quad * 8];
#pragma unroll
            for (int mt = 0; mt < MT; mt++)
                acc[mt][nt] = __builtin_amdgcn_mfma_f32_16x16x32_bf16(af[mt], bfr, acc[mt][nt], 0, 0, 0);
        }
    }

    float sh[MT][4];
#pragma unroll
    for (int mt = 0; mt < MT; mt++)
#pragma unroll
        for (int r = 0; r < 4; r++) sh[mt][r] = shift[mbase + mt * 16 + quad * 4 + r];

    if (MODE == 0) {
        float* ob = outf + (size_t)b * (2 * C * NN);
#pragma unroll
        for (int mt = 0; mt < MT; mt++)
#pragma unroll
            for (int nt = 0; nt < NT; nt++)
#pragma unroll
                for (int r = 0; r < 4; r++) {
                    const int o = mbase + mt * 16 + quad * 4 + r;
                    const int n = n0 + nbase + nt * 16 + l16;
                    ob[(size_t)o * NN + n] = fmaxf(acc[mt][nt][r] + sh[mt][r], 0.f);
                }
    } else if (MODE == 1) {
#pragma unroll
        for (int mt = 0; mt < MT; mt++)
#pragma unroll
            for (int nt = 0; nt < NT; nt++)
#pragma unroll
                for (int r = 0; r < 4; r++) {
                    const int o = mbase + mt * 16 + quad * 4 + r;
                    const int n = n0 + nbase + nt * 16 + l16;
                    outb0[((size_t)b * C + o) * NN + n] = f2bf(fmaxf(acc[mt][nt][r] + sh[mt][r], 0.f));
                }
    } else {
        unsigned short* ob16 = blockIdx.z ? outb1 : outb0;
        const float osc = blockIdx.z ? 1.f : LOG2E;   // scale K into exp2 domain
#pragma unroll
        for (int mt = 0; mt < MT; mt++)
#pragma unroll
            for (int nt = 0; nt < NT; nt++)
#pragma unroll
                for (int r = 0; r < 4; r++) {
                    const int o = mbase + mt * 16 + quad * 4 + r;
                    const int n = n0 + nbase + nt * 16 + l16;
                    ob16[((size_t)b * NN + n) * 32 + o] = f2bf(fmaxf(acc[mt][nt][r] + sh[mt][r], 0.f) * osc);
                }
    }
}

// stats: 128(m) x 128(n) scaled-KQ tile per block; online (max, sum exp2) per lane
__global__ __launch_bounds__(256) void k_stats(
    const unsigned short* __restrict__ Kt, const unsigned short* __restrict__ Qt,
    float* __restrict__ bmax, float* __restrict__ bsum)
{
    const int tid = threadIdx.x;
    const int w = tid >> 6, lane = tid & 63;
    const int quad = lane >> 4, l16 = lane & 15;
    const int b = blockIdx.z;
    const int n0 = blockIdx.x * 128, m0 = blockIdx.y * 128;
    const unsigned short* Kb = Kt + (size_t)b * NN * 32;
    const unsigned short* Qb = Qt + (size_t)b * NN * 32;

    bf16x8 kf[8], qf[2];
#pragma unroll
    for (int nt = 0; nt < 8; nt++)
        kf[nt] = *(const bf16x8*)&Kb[(size_t)(n0 + nt * 16 + l16) * 32 + quad * 8];
#pragma unroll
    for (int mt = 0; mt < 2; mt++)
        qf[mt] = *(const bf16x8*)&Qb[(size_t)(m0 + w * 32 + mt * 16 + l16) * 32 + quad * 8];

    float lmax = NEG_INF, lsum = 0.f;
#pragma unroll
    for (int mt = 0; mt < 2; mt++)
#pragma unroll
        for (int nt = 0; nt < 8; nt++) {
            f32x4 s = (f32x4){0.f, 0.f, 0.f, 0.f};
            s = __builtin_amdgcn_mfma_f32_16x16x32_bf16(qf[mt], kf[nt], s, 0, 0, 0);
            const float tmax = fmaxf(fmaxf(s[0], s[1]), fmaxf(s[2], s[3]));
            if (tmax > lmax) { lsum *= fexp2(lmax - tmax); lmax = tmax; }
            lsum += fexp2(s[0] - lmax) + fexp2(s[1] - lmax) +
                    fexp2(s[2] - lmax) + fexp2(s[3] - lmax);
        }

#pragma unroll
    for (int off = 32; off > 0; off >>= 1) {
        const float omax = __shfl_xor(lmax, off);
        const float osum = __shfl_xor(lsum, off);
        const float nmax = fmaxf(lmax, omax);
        lsum = lsum * fexp2(lmax - nmax) + osum * fexp2(omax - nmax);
        lmax = nmax;
    }
    __shared__ float smax[4], ssum[4];
    if (lane == 0) { smax[w] = lmax; ssum[w] = lsum; }
    __syncthreads();
    if (tid == 0) {
        float M = smax[0], S = ssum[0];
        for (int i = 1; i < 4; i++) {
            const float nmax = fmaxf(M, smax[i]);
            S = S * fexp2(M - nmax) + ssum[i] * fexp2(smax[i] - nmax);
            M = nmax;
        }
        const int idx = (b * 18 + blockIdx.y) * 18 + blockIdx.x;
        bmax[idx] = M;
        bsum[idx] = S;
    }
}

__global__ __launch_bounds__(256) void k_fin(
    const float* __restrict__ bmax, const float* __restrict__ bsum,
    float* __restrict__ Ms, float* __restrict__ Sinv)
{
    __shared__ float rmax[256], rsum[256];
    const int b = blockIdx.x, tid = threadIdx.x;
    float lmax = NEG_INF, lsum = 0.f;
    for (int i = tid; i < 324; i += 256) {
        const float m = bmax[b * 324 + i], s = bsum[b * 324 + i];
        const float nmax = fmaxf(lmax, m);
        lsum = lsum * fexp2(lmax - nmax) + s * fexp2(m - nmax);
        lmax = nmax;
    }
    rmax[tid] = lmax; rsum[tid] = lsum;
    __syncthreads();
    for (int st = 128; st > 0; st >>= 1) {
        if (tid < st) {
            const float m2 = rmax[tid + st], s2 = rsum[tid + st];
            const float nmax = fmaxf(rmax[tid], m2);
            rsum[tid] = rsum[tid] * fexp2(rmax[tid] - nmax) + s2 * fexp2(m2 - nmax);
            rmax[tid] = nmax;
        }
        __syncthreads();
    }
    if (tid == 0) { Ms[b] = rmax[0]; Sinv[b] = 1.f / rsum[0]; }
}

// feat v2: block = 128c x 32n output tile, m-chunks of 128.
// wave w computes S rows m in [m0+32w, m0+32w+32) for the block's 32 n,
// exp2 -> bf16 Et (XOR-swizzled 16B groups), then PV for c in [32w, 32w+32).
__global__ __launch_bounds__(256) void k_feat(
    const unsigned short* __restrict__ Kt, const unsigned short* __restrict__ Qt,
    const unsigned short* __restrict__ Vf, const float* __restrict__ Ms,
    const float* __restrict__ Sinv, float* __restrict__ out)
{
    __shared__ __align__(16) unsigned short Et[32][128];   // [n][m], 8 KB, XOR-swizzled
    const int tid = threadIdx.x;
    const int w = tid >> 6, lane = tid & 63;
    const int quad = lane >> 4, l16 = lane & 15;
    const int b = blockIdx.y, n0 = blockIdx.x * 32;
    const unsigned short* Kb = Kt + (size_t)b * NN * 32;
    const unsigned short* Qb = Qt + (size_t)b * NN * 32;
    const unsigned short* Vb = Vf + (size_t)b * C * NN;
    const float M = Ms[b], Si = Sinv[b];
    const int swz = l16 & 7;

    bf16x8 kf[2];
#pragma unroll
    for (int nt = 0; nt < 2; nt++)
        kf[nt] = *(const bf16x8*)&Kb[(size_t)(n0 + nt * 16 + l16) * 32 + quad * 8];

    f32x4 acc[2][2];
#pragma unroll
    for (int i = 0; i < 2; i++)
#pragma unroll
        for (int j = 0; j < 2; j++) acc[i][j] = (f32x4){0.f, 0.f, 0.f, 0.f};

    for (int m0 = 0; m0 < NN; m0 += 128) {
        __syncthreads();
        // ---- S phase: wave w covers m [m0+32w, +32) ----
#pragma unroll
        for (int mt = 0; mt < 2; mt++) {
            const bf16x8 qf = *(const bf16x8*)&Qb[(size_t)(m0 + w * 32 + mt * 16 + l16) * 32 + quad * 8];
#pragma unroll
            for (int nt = 0; nt < 2; nt++) {
                f32x4 s = (f32x4){0.f, 0.f, 0.f, 0.f};
                s = __builtin_amdgcn_mfma_f32_16x16x32_bf16(qf, kf[nt], s, 0, 0, 0);
                const unsigned int u0 = pk2bf(fexp2(s[0] - M), fexp2(s[1] - M));
                const unsigned int u1 = pk2bf(fexp2(s[2] - M), fexp2(s[3] - M));
                const int row  = nt * 16 + l16;
                const int g    = 4 * w + 2 * mt + (quad >> 1);
                const int phys = g ^ swz;
                *(uint2*)&Et[row][phys * 8 + (quad & 1) * 4] = make_uint2(u0, u1);
            }
        }
        __syncthreads();
        // ---- PV phase: wave w -> c in [32w, +32) ----
#pragma unroll
        for (int kt = 0; kt < 4; kt++) {
            const bf16x8 v0 = *(const bf16x8*)&Vb[(size_t)(w * 32 + l16) * NN + m0 + kt * 32 + quad * 8];
            const bf16x8 v1 = *(const bf16x8*)&Vb[(size_t)(w * 32 + 16 + l16) * NN + m0 + kt * 32 + quad * 8];
#pragma unroll
            for (int nt = 0; nt < 2; nt++) {
                const int row  = nt * 16 + l16;
                const int phys = (kt * 4 + quad) ^ swz;
                const bf16x8 ef = *(const bf16x8*)&Et[row][phys * 8];
                acc[0][nt] = __builtin_amdgcn_mfma_f32_16x16x32_bf16(v0, ef, acc[0][nt], 0, 0, 0);
                acc[1][nt] = __builtin_amdgcn_mfma_f32_16x16x32_bf16(v1, ef, acc[1][nt], 0, 0, 0);
            }
        }
    }

    float* ob = out + (size_t)b * 2 * C * NN + (size_t)C * NN + n0;
#pragma unroll
    for (int ct = 0; ct < 2; ct++)
#pragma unroll
        for (int nt = 0; nt < 2; nt++)
#pragma unroll
            for (int r = 0; r < 4; r++) {
                const int c = w * 32 + ct * 16 + quad * 4 + r;
                ob[(size_t)c * NN + nt * 16 + l16] = acc[ct][nt][r] * Si;
            }
}

extern "C" void kernel_launch(void* const* d_in, const int* in_sizes, int n_in,
                              void* d_out, int out_size, void* d_ws, size_t ws_size,
                              hipStream_t stream)
{
    const float* x_en   = (const float*)d_in[0];
    const float* x_de   = (const float*)d_in[1];
    const float* x_cat  = (const float*)d_in[2];
    const float* w_kq   = (const float*)d_in[3];
    const float* kq_g   = (const float*)d_in[4];
    const float* kq_b   = (const float*)d_in[5];
    const float* kq_m   = (const float*)d_in[6];
    const float* kq_v   = (const float*)d_in[7];
    const float* w_v    = (const float*)d_in[8];
    const float* v_g    = (const float*)d_in[9];
    const float* v_b    = (const float*)d_in[10];
    const float* v_m    = (const float*)d_in[11];
    const float* v_v    = (const float*)d_in[12];
    const float* w_red  = (const float*)d_in[13];
    const float* red_g  = (const float*)d_in[14];
    const float* red_b  = (const float*)d_in[15];
    const float* red_m  = (const float*)d_in[16];
    const float* red_v  = (const float*)d_in[17];

    unsigned short* Kt      = (unsigned short*)d_ws;
    unsigned short* Qt      = Kt + 1179648;
    unsigned short* Vf      = Qt + 1179648;
    unsigned short* wkq_bf  = Vf + 4718592;
    unsigned short* wv_bf   = wkq_bf + 4096;
    unsigned short* wred_bf = wv_bf + 16384;
    float* bmax = (float*)(wred_bf + 32768);
    float* bsum = bmax + 16 * 324;
    float* Ms   = bsum + 16 * 324;
    float* Sinv = Ms + 16;
    float* kq_sh  = Sinv + 16;
    float* v_sh   = kq_sh + 32;
    float* red_sh = v_sh + 128;
    float* out  = (float*)d_out;

    k_wprep<<<208, 256, 0, stream>>>(
        w_kq, kq_g, kq_b, kq_m, kq_v,
        w_v, v_g, v_b, v_m, v_v,
        w_red, red_g, red_b, red_m, red_v,
        wkq_bf, wv_bf, wred_bf, kq_sh, v_sh, red_sh);

    k_conv<128, 32, 128, 2><<<dim3(18, 16, 2), 256, 0, stream>>>(
        x_en, x_de, (size_t)C * NN, wkq_bf, kq_sh, nullptr, Kt, Qt);
    k_conv<256, 128, 64, 0><<<dim3(36, 16), 256, 0, stream>>>(
        x_cat, nullptr, (size_t)(2 * C) * NN, wred_bf, red_sh, out, nullptr, nullptr);
    k_conv<128, 128, 64, 1><<<dim3(36, 16), 256, 0, stream>>>(
        out, nullptr, (size_t)(2 * C) * NN, wv_bf, v_sh, nullptr, Vf, nullptr);

    k_stats<<<dim3(18, 18, 16), 256, 0, stream>>>(Kt, Qt, bmax, bsum);
    k_fin  <<<16, 256, 0, stream>>>(bmax, bsum, Ms, Sinv);
    k_feat <<<dim3(72, 16), 256, 0, stream>>>(Kt, Qt, Vf, Ms, Sinv, out);
}

// Round 5
// 250.981 us; speedup vs baseline: 1.1617x; 1.1617x over previous
//
#include <hip/hip_runtime.h>
#include <math.h>

#define C    128
#define C4   32
#define NN   2304          // 48*48
#define BN_EPS 1e-5f
#define NEG_INF -3.402823466e38f
#define LOG2E 1.4426950408889634f

typedef short bf16x8 __attribute__((ext_vector_type(8)));
typedef float f32x4 __attribute__((ext_vector_type(4)));

// barrier that only drains LDS (lgkmcnt) — leaves prefetched global loads in flight.
// Safe when the barrier only orders LDS traffic (__syncthreads would drain vmcnt(0)).
#define SOFT_BARRIER() asm volatile("s_waitcnt lgkmcnt(0)\n\ts_barrier" ::: "memory")

__device__ inline unsigned short f2bf(float f) {
    unsigned int u = __float_as_uint(f);
    u += 0x7fffu + ((u >> 16) & 1u);
    return (unsigned short)(u >> 16);
}

// pack two fp32 -> packed bf16 pair (low = a, high = b), RNE
__device__ inline unsigned int pk2bf(float a, float b) {
#if __has_builtin(__builtin_amdgcn_cvt_pk_bf16_f32)
    typedef __bf16 bf2 __attribute__((ext_vector_type(2)));
    bf2 v = __builtin_amdgcn_cvt_pk_bf16_f32(a, b);
    return __builtin_bit_cast(unsigned int, v);
#else
    unsigned int ua = __float_as_uint(a); ua += 0x7fffu + ((ua >> 16) & 1u);
    unsigned int ub = __float_as_uint(b); ub += 0x7fffu + ((ub >> 16) & 1u);
    return __builtin_amdgcn_perm(ub, ua, 0x07060302u);
#endif
}

__device__ inline float fexp2(float x) {
#if __has_builtin(__builtin_amdgcn_exp2f)
    return __builtin_amdgcn_exp2f(x);
#else
    return __expf(x * 0.69314718055994531f);
#endif
}

// ---------------- workspace layout ----------------
// ushort region:
//   Kt  [16][2304][32]  @0         (1179648)   NOTE: K pre-scaled by log2(e)
//   Qt  [16][2304][32]  @1179648   (1179648)
//   Vf  [16][128][2304] @2359296   (4718592)
//   wkq_bf [32][128]    @7077888   (4096)
//   wv_bf  [128][128]   @7081984   (16384)
//   wred_bf[128][256]   @7098368   (32768)
// float region:
//   bmax[16*324], bsum[16*324], Ms[16], Sinv[16], kq_sh[32], v_sh[128], red_sh[128]

__global__ __launch_bounds__(256) void k_wprep(
    const float* __restrict__ wkq, const float* __restrict__ kq_g,
    const float* __restrict__ kq_b, const float* __restrict__ kq_m,
    const float* __restrict__ kq_v,
    const float* __restrict__ wv, const float* __restrict__ v_g,
    const float* __restrict__ v_b, const float* __restrict__ v_m,
    const float* __restrict__ v_v,
    const float* __restrict__ wred, const float* __restrict__ red_g,
    const float* __restrict__ red_b, const float* __restrict__ red_m,
    const float* __restrict__ red_v,
    unsigned short* __restrict__ wkq_bf, unsigned short* __restrict__ wv_bf,
    unsigned short* __restrict__ wred_bf,
    float* __restrict__ kq_sh, float* __restrict__ v_sh, float* __restrict__ red_sh)
{
    const int t = blockIdx.x * 256 + threadIdx.x;
    if (t < 4096) {
        const int o = t >> 7;
        const float sc = kq_g[o] * rsqrtf(kq_v[o] + BN_EPS);
        wkq_bf[t] = f2bf(wkq[t] * sc);
        if ((t & 127) == 0) kq_sh[o] = kq_b[o] - kq_m[o] * sc;
    } else if (t < 4096 + 16384) {
        const int e = t - 4096;
        const int o = e >> 7;
        const float sc = v_g[o] * rsqrtf(v_v[o] + BN_EPS);
        wv_bf[e] = f2bf(wv[e] * sc);
        if ((e & 127) == 0) v_sh[o] = v_b[o] - v_m[o] * sc;
    } else if (t < 4096 + 16384 + 32768) {
        const int e = t - 20480;
        const int o = e >> 8;
        const float sc = red_g[o] * rsqrtf(red_v[o] + BN_EPS);
        wred_bf[e] = f2bf(wred[e] * sc);
        if ((e & 255) == 0) red_sh[o] = red_b[o] - red_m[o] * sc;
    }
}

// ---- K/Q conv via MFMA: bf16 transposed out [b][n][32o]; K (z==0) scaled by log2(e)
__global__ __launch_bounds__(256) void k_kq(
    const float* __restrict__ x0, const float* __restrict__ x1,
    const unsigned short* __restrict__ wbf, const float* __restrict__ shift,
    unsigned short* __restrict__ Kt, unsigned short* __restrict__ Qt)
{
    constexpr int NTILE = 128, R = 8;
    __shared__ unsigned short Xs[NTILE][40];

    const int tid = threadIdx.x;
    const int w = tid >> 6, lane = tid & 63;
    const int quad = lane >> 4, l16 = lane & 15;
    const int b = blockIdx.y, n0 = blockIdx.x * NTILE;
    const int nbase = w * 32;

    const float* xin = (blockIdx.z ? x1 : x0) + (size_t)b * C * NN;
    const int p = tid & 15, g = tid >> 4;

    f32x4 acc[2][2];
#pragma unroll
    for (int mt = 0; mt < 2; mt++)
#pragma unroll
        for (int nt = 0; nt < 2; nt++) acc[mt][nt] = (f32x4){0.f, 0.f, 0.f, 0.f};

    for (int c0 = 0; c0 < C; c0 += 32) {
        __syncthreads();
        {
            const float* xr = xin + (size_t)(c0 + 2 * p) * NN + n0 + g * R;
            float av[R], bv[R];
#pragma unroll
            for (int i4 = 0; i4 < R; i4 += 4) {
                *(float4*)&av[i4] = *(const float4*)&xr[i4];
                *(float4*)&bv[i4] = *(const float4*)&xr[NN + i4];
            }
            unsigned int* Xw = (unsigned int*)Xs;
#pragma unroll
            for (int i = 0; i < R; i++)
                Xw[(g * R + i) * 20 + p] = pk2bf(av[i], bv[i]);
        }
        __syncthreads();
        bf16x8 af[2];
#pragma unroll
        for (int mt = 0; mt < 2; mt++)
            af[mt] = *(const bf16x8*)&wbf[(size_t)(mt * 16 + l16) * C + c0 + quad * 8];
#pragma unroll
        for (int nt = 0; nt < 2; nt++) {
            const bf16x8 bfr = *(const bf16x8*)&Xs[nbase + nt * 16 + l16][quad * 8];
#pragma unroll
            for (int mt = 0; mt < 2; mt++)
                acc[mt][nt] = __builtin_amdgcn_mfma_f32_16x16x32_bf16(af[mt], bfr, acc[mt][nt], 0, 0, 0);
        }
    }

    unsigned short* ob16 = blockIdx.z ? Qt : Kt;
    const float osc = blockIdx.z ? 1.f : LOG2E;
#pragma unroll
    for (int mt = 0; mt < 2; mt++)
#pragma unroll
        for (int nt = 0; nt < 2; nt++)
#pragma unroll
            for (int r = 0; r < 4; r++) {
                const int o = mt * 16 + quad * 4 + r;
                const int n = n0 + nbase + nt * 16 + l16;
                const float sh = shift[o];
                ob16[((size_t)b * NN + n) * 32 + o] =
                    f2bf(fmaxf(acc[mt][nt][r] + sh, 0.f) * osc);
            }
}

// ---- fused reduce-conv + V-conv ----
// red: x[o][n] = relu(bn(wred * xcat)) -> fp32 d_out ch 0..127 AND bf16 LDS tile
// v:   V[o][n] = relu(bn(wv * x))      -> bf16 Vf  (x consumed from LDS, no global round-trip)
__global__ __launch_bounds__(256) void k_redv(
    const float* __restrict__ xcat,
    const unsigned short* __restrict__ wred_bf, const float* __restrict__ red_sh,
    const unsigned short* __restrict__ wv_bf,  const float* __restrict__ v_sh,
    float* __restrict__ out, unsigned short* __restrict__ Vf)
{
    __shared__ unsigned short Xs[64][40];     // staging for xcat chunks
    __shared__ unsigned int   Xv[64 * 65];    // x as bf16-pairs: [cp][n], stride 65 dwords

    const int tid = threadIdx.x;
    const int w = tid >> 6, lane = tid & 63;
    const int quad = lane >> 4, l16 = lane & 15;
    const int b = blockIdx.y, n0 = blockIdx.x * 64;
    const float* xin = xcat + (size_t)b * 2 * C * NN;
    const int p = tid & 15, g = tid >> 4;

    f32x4 acc[2][4];
#pragma unroll
    for (int mt = 0; mt < 2; mt++)
#pragma unroll
        for (int nt = 0; nt < 4; nt++) acc[mt][nt] = (f32x4){0.f, 0.f, 0.f, 0.f};

    // ---- red phase: 256-c sweep ----
    for (int c0 = 0; c0 < 2 * C; c0 += 32) {
        __syncthreads();
        {
            const float* xr = xin + (size_t)(c0 + 2 * p) * NN + n0 + g * 4;
            float4 av = *(const float4*)&xr[0];
            float4 bv = *(const float4*)&xr[NN];
            unsigned int* Xw = (unsigned int*)Xs;
            Xw[(g * 4 + 0) * 20 + p] = pk2bf(av.x, bv.x);
            Xw[(g * 4 + 1) * 20 + p] = pk2bf(av.y, bv.y);
            Xw[(g * 4 + 2) * 20 + p] = pk2bf(av.z, bv.z);
            Xw[(g * 4 + 3) * 20 + p] = pk2bf(av.w, bv.w);
        }
        __syncthreads();
        bf16x8 af[2];
#pragma unroll
        for (int mt = 0; mt < 2; mt++)
            af[mt] = *(const bf16x8*)&wred_bf[(size_t)(w * 32 + mt * 16 + l16) * (2 * C) + c0 + quad * 8];
#pragma unroll
        for (int nt = 0; nt < 4; nt++) {
            const bf16x8 bfr = *(const bf16x8*)&Xs[nt * 16 + l16][quad * 8];
#pragma unroll
            for (int mt = 0; mt < 2; mt++)
                acc[mt][nt] = __builtin_amdgcn_mfma_f32_16x16x32_bf16(af[mt], bfr, acc[mt][nt], 0, 0, 0);
        }
    }

    // red epilogue: fp32 -> d_out, bf16 pairs -> Xv[cp][n]
    {
        float* ob = out + (size_t)b * (2 * C * NN);
#pragma unroll
        for (int mt = 0; mt < 2; mt++) {
            float sh[4];
#pragma unroll
            for (int r = 0; r < 4; r++) sh[r] = red_sh[w * 32 + mt * 16 + quad * 4 + r];
#pragma unroll
            for (int nt = 0; nt < 4; nt++) {
                const int n = n0 + nt * 16 + l16;
                float v[4];
#pragma unroll
                for (int r = 0; r < 4; r++) {
                    const int o = w * 32 + mt * 16 + quad * 4 + r;
                    v[r] = fmaxf(acc[mt][nt][r] + sh[r], 0.f);
                    ob[(size_t)o * NN + n] = v[r];
                }
                const int op0 = 16 * w + mt * 8 + quad * 2;   // c-pair row
                Xv[(op0 + 0) * 65 + nt * 16 + l16] = pk2bf(v[0], v[1]);
                Xv[(op0 + 1) * 65 + nt * 16 + l16] = pk2bf(v[2], v[3]);
            }
        }
    }
    SOFT_BARRIER();   // order Xv LDS traffic only; fp32 out-stores stay in flight

    // ---- V phase: 128-c sweep reading x from Xv ----
    f32x4 vacc[2][4];
#pragma unroll
    for (int mt = 0; mt < 2; mt++)
#pragma unroll
        for (int nt = 0; nt < 4; nt++) vacc[mt][nt] = (f32x4){0.f, 0.f, 0.f, 0.f};

    for (int c0 = 0; c0 < C; c0 += 32) {
        bf16x8 af[2];
#pragma unroll
        for (int mt = 0; mt < 2; mt++)
            af[mt] = *(const bf16x8*)&wv_bf[(size_t)(w * 32 + mt * 16 + l16) * C + c0 + quad * 8];
#pragma unroll
        for (int nt = 0; nt < 4; nt++) {
            const int col = nt * 16 + l16;
            const int cp0 = c0 / 2 + quad * 4;
            uint4 u;
            u.x = Xv[(cp0 + 0) * 65 + col];
            u.y = Xv[(cp0 + 1) * 65 + col];
            u.z = Xv[(cp0 + 2) * 65 + col];
            u.w = Xv[(cp0 + 3) * 65 + col];
            const bf16x8 bfr = __builtin_bit_cast(bf16x8, u);
#pragma unroll
            for (int mt = 0; mt < 2; mt++)
                vacc[mt][nt] = __builtin_amdgcn_mfma_f32_16x16x32_bf16(af[mt], bfr, vacc[mt][nt], 0, 0, 0);
        }
    }

#pragma unroll
    for (int mt = 0; mt < 2; mt++) {
        float sh[4];
#pragma unroll
        for (int r = 0; r < 4; r++) sh[r] = v_sh[w * 32 + mt * 16 + quad * 4 + r];
#pragma unroll
        for (int nt = 0; nt < 4; nt++)
#pragma unroll
            for (int r = 0; r < 4; r++) {
                const int o = w * 32 + mt * 16 + quad * 4 + r;
                const int n = n0 + nt * 16 + l16;
                Vf[((size_t)b * C + o) * NN + n] = f2bf(fmaxf(vacc[mt][nt][r] + sh[r], 0.f));
            }
    }
}

// stats: 128(m) x 128(n) scaled-KQ tile; all 16 MFMAs first, then bulk reduce
__global__ __launch_bounds__(256) void k_stats(
    const unsigned short* __restrict__ Kt, const unsigned short* __restrict__ Qt,
    float* __restrict__ bmax, float* __restrict__ bsum)
{
    const int tid = threadIdx.x;
    const int w = tid >> 6, lane = tid & 63;
    const int quad = lane >> 4, l16 = lane & 15;
    const int b = blockIdx.z;
    const int n0 = blockIdx.x * 128, m0 = blockIdx.y * 128;
    const unsigned short* Kb = Kt + (size_t)b * NN * 32;
    const unsigned short* Qb = Qt + (size_t)b * NN * 32;

    bf16x8 kf[8], qf[2];
#pragma unroll
    for (int nt = 0; nt < 8; nt++)
        kf[nt] = *(const bf16x8*)&Kb[(size_t)(n0 + nt * 16 + l16) * 32 + quad * 8];
#pragma unroll
    for (int mt = 0; mt < 2; mt++)
        qf[mt] = *(const bf16x8*)&Qb[(size_t)(m0 + w * 32 + mt * 16 + l16) * 32 + quad * 8];

    f32x4 s[16];
#pragma unroll
    for (int mt = 0; mt < 2; mt++)
#pragma unroll
        for (int nt = 0; nt < 8; nt++) {
            f32x4 z = (f32x4){0.f, 0.f, 0.f, 0.f};
            s[mt * 8 + nt] = __builtin_amdgcn_mfma_f32_16x16x32_bf16(qf[mt], kf[nt], z, 0, 0, 0);
        }

    float lmax = NEG_INF;
#pragma unroll
    for (int i = 0; i < 16; i++)
        lmax = fmaxf(lmax, fmaxf(fmaxf(s[i][0], s[i][1]), fmaxf(s[i][2], s[i][3])));
    float lsum = 0.f;
#pragma unroll
    for (int i = 0; i < 16; i++)
        lsum += fexp2(s[i][0] - lmax) + fexp2(s[i][1] - lmax) +
                fexp2(s[i][2] - lmax) + fexp2(s[i][3] - lmax);

#pragma unroll
    for (int off = 32; off > 0; off >>= 1) {
        const float omax = __shfl_xor(lmax, off);
        const float osum = __shfl_xor(lsum, off);
        const float nmax = fmaxf(lmax, omax);
        lsum = lsum * fexp2(lmax - nmax) + osum * fexp2(omax - nmax);
        lmax = nmax;
    }
    __shared__ float smax[4], ssum[4];
    if (lane == 0) { smax[w] = lmax; ssum[w] = lsum; }
    __syncthreads();
    if (tid == 0) {
        float M = smax[0], S = ssum[0];
        for (int i = 1; i < 4; i++) {
            const float nmax = fmaxf(M, smax[i]);
            S = S * fexp2(M - nmax) + ssum[i] * fexp2(smax[i] - nmax);
            M = nmax;
        }
        const int idx = (b * 18 + blockIdx.y) * 18 + blockIdx.x;
        bmax[idx] = M;
        bsum[idx] = S;
    }
}

__global__ __launch_bounds__(256) void k_fin(
    const float* __restrict__ bmax, const float* __restrict__ bsum,
    float* __restrict__ Ms, float* __restrict__ Sinv)
{
    __shared__ float rmax[256], rsum[256];
    const int b = blockIdx.x, tid = threadIdx.x;
    float lmax = NEG_INF, lsum = 0.f;
    for (int i = tid; i < 324; i += 256) {
        const float m = bmax[b * 324 + i], s = bsum[b * 324 + i];
        const float nmax = fmaxf(lmax, m);
        lsum = lsum * fexp2(lmax - nmax) + s * fexp2(m - nmax);
        lmax = nmax;
    }
    rmax[tid] = lmax; rsum[tid] = lsum;
    __syncthreads();
    for (int st = 128; st > 0; st >>= 1) {
        if (tid < st) {
            const float m2 = rmax[tid + st], s2 = rsum[tid + st];
            const float nmax = fmaxf(rmax[tid], m2);
            rsum[tid] = rsum[tid] * fexp2(rmax[tid] - nmax) + s2 * fexp2(m2 - nmax);
            rmax[tid] = nmax;
        }
        __syncthreads();
    }
    if (tid == 0) { Ms[b] = rmax[0]; Sinv[b] = 1.f / rsum[0]; }
}

// feat: block = 128c x 64n, m-chunks of 64, register-prefetched Q/V across
// soft (lgkm-only) barriers so next chunk's global loads overlap this chunk.
__global__ __launch_bounds__(256) void k_feat(
    const unsigned short* __restrict__ Kt, const unsigned short* __restrict__ Qt,
    const unsigned short* __restrict__ Vf, const float* __restrict__ Ms,
    const float* __restrict__ Sinv, float* __restrict__ out)
{
    __shared__ __align__(16) unsigned short Et[64][72];
    const int tid = threadIdx.x;
    const int w = tid >> 6, lane = tid & 63;
    const int quad = lane >> 4, l16 = lane & 15;
    const int b = blockIdx.y, n0 = blockIdx.x * 64;
    const unsigned short* Kb = Kt + (size_t)b * NN * 32;
    const unsigned short* Qb = Qt + (size_t)b * NN * 32;
    const unsigned short* Vb = Vf + (size_t)b * C * NN;
    const float M = Ms[b], Si = Sinv[b];

    bf16x8 kf[4];
#pragma unroll
    for (int nt = 0; nt < 4; nt++)
        kf[nt] = *(const bf16x8*)&Kb[(size_t)(n0 + nt * 16 + l16) * 32 + quad * 8];

    f32x4 acc[2][4];
#pragma unroll
    for (int i = 0; i < 2; i++)
#pragma unroll
        for (int j = 0; j < 4; j++) acc[i][j] = (f32x4){0.f, 0.f, 0.f, 0.f};

    // preload chunk 0
    bf16x8 qc = *(const bf16x8*)&Qb[(size_t)(w * 16 + l16) * 32 + quad * 8];
    bf16x8 vc[2][2];
#pragma unroll
    for (int ct = 0; ct < 2; ct++)
#pragma unroll
        for (int ks = 0; ks < 2; ks++)
            vc[ct][ks] = *(const bf16x8*)&Vb[(size_t)(w * 32 + ct * 16 + l16) * NN + ks * 32 + quad * 8];

    for (int m0 = 0; m0 < NN; m0 += 64) {
        // S phase
        f32x4 s[4];
#pragma unroll
        for (int nt = 0; nt < 4; nt++) {
            f32x4 z = (f32x4){0.f, 0.f, 0.f, 0.f};
            s[nt] = __builtin_amdgcn_mfma_f32_16x16x32_bf16(qc, kf[nt], z, 0, 0, 0);
        }
        // issue next chunk's global loads NOW (they stay in flight across barriers)
        const int m1 = (m0 + 64 < NN) ? m0 + 64 : 0;
        bf16x8 qn = *(const bf16x8*)&Qb[(size_t)(m1 + w * 16 + l16) * 32 + quad * 8];
        bf16x8 vn[2][2];
#pragma unroll
        for (int ct = 0; ct < 2; ct++)
#pragma unroll
            for (int ks = 0; ks < 2; ks++)
                vn[ct][ks] = *(const bf16x8*)&Vb[(size_t)(w * 32 + ct * 16 + l16) * NN + m1 + ks * 32 + quad * 8];

        // exp2 + pack + Et write
#pragma unroll
        for (int nt = 0; nt < 4; nt++) {
            const unsigned int u0 = pk2bf(fexp2(s[nt][0] - M), fexp2(s[nt][1] - M));
            const unsigned int u1 = pk2bf(fexp2(s[nt][2] - M), fexp2(s[nt][3] - M));
            *(uint2*)&Et[nt * 16 + l16][w * 16 + quad * 4] = make_uint2(u0, u1);
        }
        SOFT_BARRIER();
        // PV phase
#pragma unroll
        for (int ks = 0; ks < 2; ks++) {
#pragma unroll
            for (int nt = 0; nt < 4; nt++) {
                const bf16x8 ef = *(const bf16x8*)&Et[nt * 16 + l16][ks * 32 + quad * 8];
                acc[0][nt] = __builtin_amdgcn_mfma_f32_16x16x32_bf16(vc[0][ks], ef, acc[0][nt], 0, 0, 0);
                acc[1][nt] = __builtin_amdgcn_mfma_f32_16x16x32_bf16(vc[1][ks], ef, acc[1][nt], 0, 0, 0);
            }
        }
        SOFT_BARRIER();
        qc = qn;
#pragma unroll
        for (int ct = 0; ct < 2; ct++)
#pragma unroll
            for (int ks = 0; ks < 2; ks++) vc[ct][ks] = vn[ct][ks];
    }

    float* ob = out + (size_t)b * 2 * C * NN + (size_t)C * NN + n0;
#pragma unroll
    for (int ct = 0; ct < 2; ct++)
#pragma unroll
        for (int nt = 0; nt < 4; nt++)
#pragma unroll
            for (int r = 0; r < 4; r++) {
                const int c = w * 32 + ct * 16 + quad * 4 + r;
                ob[(size_t)c * NN + nt * 16 + l16] = acc[ct][nt][r] * Si;
            }
}

extern "C" void kernel_launch(void* const* d_in, const int* in_sizes, int n_in,
                              void* d_out, int out_size, void* d_ws, size_t ws_size,
                              hipStream_t stream)
{
    const float* x_en   = (const float*)d_in[0];
    const float* x_de   = (const float*)d_in[1];
    const float* x_cat  = (const float*)d_in[2];
    const float* w_kq   = (const float*)d_in[3];
    const float* kq_g   = (const float*)d_in[4];
    const float* kq_b   = (const float*)d_in[5];
    const float* kq_m   = (const float*)d_in[6];
    const float* kq_v   = (const float*)d_in[7];
    const float* w_v    = (const float*)d_in[8];
    const float* v_g    = (const float*)d_in[9];
    const float* v_b    = (const float*)d_in[10];
    const float* v_m    = (const float*)d_in[11];
    const float* v_v    = (const float*)d_in[12];
    const float* w_red  = (const float*)d_in[13];
    const float* red_g  = (const float*)d_in[14];
    const float* red_b  = (const float*)d_in[15];
    const float* red_m  = (const float*)d_in[16];
    const float* red_v  = (const float*)d_in[17];

    unsigned short* Kt      = (unsigned short*)d_ws;
    unsigned short* Qt      = Kt + 1179648;
    unsigned short* Vf      = Qt + 1179648;
    unsigned short* wkq_bf  = Vf + 4718592;
    unsigned short* wv_bf   = wkq_bf + 4096;
    unsigned short* wred_bf = wv_bf + 16384;
    float* bmax = (float*)(wred_bf + 32768);
    float* bsum = bmax + 16 * 324;
    float* Ms   = bsum + 16 * 324;
    float* Sinv = Ms + 16;
    float* kq_sh  = Sinv + 16;
    float* v_sh   = kq_sh + 32;
    float* red_sh = v_sh + 128;
    float* out  = (float*)d_out;

    k_wprep<<<208, 256, 0, stream>>>(
        w_kq, kq_g, kq_b, kq_m, kq_v,
        w_v, v_g, v_b, v_m, v_v,
        w_red, red_g, red_b, red_m, red_v,
        wkq_bf, wv_bf, wred_bf, kq_sh, v_sh, red_sh);

    k_kq  <<<dim3(18, 16, 2), 256, 0, stream>>>(x_en, x_de, wkq_bf, kq_sh, Kt, Qt);
    k_redv<<<dim3(36, 16), 256, 0, stream>>>(x_cat, wred_bf, red_sh, wv_bf, v_sh, out, Vf);

    k_stats<<<dim3(18, 18, 16), 256, 0, stream>>>(Kt, Qt, bmax, bsum);
    k_fin  <<<16, 256, 0, stream>>>(bmax, bsum, Ms, Sinv);
    k_feat <<<dim3(36, 16), 256, 0, stream>>>(Kt, Qt, Vf, Ms, Sinv, out);
}